// Round 6
// baseline (178.392 us; speedup 1.0000x reference)
//
#include <hip/hip_runtime.h>

typedef unsigned short u16;
typedef unsigned int   u32;
typedef __attribute__((ext_vector_type(8))) short bf16x8;
typedef __attribute__((ext_vector_type(4))) float f32x4;
typedef __attribute__((ext_vector_type(2))) unsigned int u32x2;

__device__ __forceinline__ float bf2f(u16 u) { return __uint_as_float(((u32)u) << 16); }
// round-half-up (ties away): identical to RNE except exact ties; 2 VALU ops.
__device__ __forceinline__ u16 f2bf(float f) {
    return (u16)((__float_as_uint(f) + 0x8000u) >> 16);
}
// packed RNE f32->bf16 pair: one VALU op for two conversions
__device__ __forceinline__ u32 cvt_pk_bf16(float lo, float hi) {
    u32 r;
    asm("v_cvt_pk_bf16_f32 %0, %1, %2" : "=v"(r) : "v"(lo), "v"(hi));
    return r;
}
__device__ __forceinline__ void gload16(const void* g, void* l) {
    __builtin_amdgcn_global_load_lds((const __attribute__((address_space(1))) void*)g,
                                     (__attribute__((address_space(3))) void*)l, 16, 0, 0);
}
#define VMCNT(n) asm volatile("s_waitcnt vmcnt(" #n ")" ::: "memory")

// ---------------------------------------------------------------------------
// Fused fp32->bf16 conversion for hs + Wq + Wk + Wv (contiguous dsts in ws).
// ---------------------------------------------------------------------------
struct us4 { u16 x, y, z, w; };
__global__ void cvt_all(const float* __restrict__ hs, const float* __restrict__ wq,
                        const float* __restrict__ wk, const float* __restrict__ wv,
                        u16* __restrict__ dst)
{
    int i = blockIdx.x * blockDim.x + threadIdx.x;
    const int stride = gridDim.x * blockDim.x;
    us4* d4 = (us4*)dst;
    for (; i < 1835008; i += stride) {
        const float4* s4;
        int j = i;
        if (j < 1048576)      { s4 = (const float4*)hs; }
        else if (j < 1310720) { s4 = (const float4*)wq; j -= 1048576; }
        else if (j < 1572864) { s4 = (const float4*)wk; j -= 1310720; }
        else                  { s4 = (const float4*)wv; j -= 1572864; }
        float4 v = s4[j];
        us4 o;
        o.x = f2bf(v.x); o.y = f2bf(v.y); o.z = f2bf(v.z); o.w = f2bf(v.w);
        d4[i] = o;
    }
}

// ---------------------------------------------------------------------------
// Kernel 1: fused QKV projection — R5 rewrite to the m97-structure 128x128
// tile (R4 analysis: qkv was ~90-95 us of the 166 us launch, running the
// ladder's ~300 TF 64x128 structure; 128^2 with 4x4 frags/wave is the
// verified ~900 TF point).
//   BM=BN=128, BK=64; 4 waves, wave w owns 64x64 quadrant (wr=w>>1, wc=w&1);
//   per K-step: 32 MFMA : 16 ds_read_b128 : 8 global_load_lds(16B)/thread-
//   group — 2x m97's exact ratios.  XOR-swizzled LDS (row&7), single-buffer
//   2-barrier loop.  Grid (24, 32): blockIdx.x = mat*8+cb fastest; 24%8==0
//   so XCD r owns cb==r for all 3 mats -> W slice 0.75 MB L2-resident; the
//   3 blocks sharing an hs slice are dispatch-adjacent on the same XCD.
//   Epilogue: per-wave 64x72 LDS transpose strip (smem reused after barrier,
//   36 KB total), 16B coalesced stores.  Q,K out [b,h,n,d]; V out [b,h,d,n].
// ---------------------------------------------------------------------------
__global__ __launch_bounds__(256) void qkv_gemm(
    const u16* __restrict__ hs,
    const u16* __restrict__ Wq, const u16* __restrict__ Wk, const u16* __restrict__ Wv,
    const float* __restrict__ bq, const float* __restrict__ bk, const float* __restrict__ bv,
    u16* __restrict__ oq, u16* __restrict__ ok, u16* __restrict__ ovt)
{
    __shared__ u16 smem[18432];        // sA 128x64 [0,8192), sB 128x64 [8192,16384)
    u16* sA = smem;                    // epilogue: 4 waves x 64x72 strips [0,18432)
    u16* sB = smem + 8192;

    const int tid  = threadIdx.x;
    const int lane = tid & 63;
    const int w    = tid >> 6;
    const int c15  = lane & 15;
    const int q4   = lane >> 4;
    const int mat  = blockIdx.x >> 3;   // 0=q 1=k 2=v
    const int cb   = blockIdx.x & 7;    // col block (128 cols = 2 heads)
    const int rb   = blockIdx.y;        // row block (128 rows)
    const int wr   = w >> 1, wc = w & 1;

    const u16*   W    = (mat == 0) ? Wq : (mat == 1 ? Wk : Wv);
    const float* bias = (mat == 0) ? bq : (mat == 1 ? bk : bv);

    f32x4 acc[4][4] = {};

    // staging: each 128x64 tile = 1024 16B chunks, 4/thread (chunk c=p*256+tid)
    //   row = 32p + (tid>>3), src col XOR-swizzled by row&7; LDS dest linear.
    const int rs = tid >> 3;
    const int cs = ((tid & 7) ^ (rs & 7)) * 8;
    const u16* gA = hs + (rb * 128) * 1024;
    const u16* gB = W + (cb * 128) * 1024;

    for (int kb = 0; kb < 1024; kb += 64) {
        __syncthreads();
#pragma unroll
        for (int p = 0; p < 4; ++p)
            gload16(gA + (rs + 32 * p) * 1024 + kb + cs, sA + p * 2048 + w * 512);
#pragma unroll
        for (int p = 0; p < 4; ++p)
            gload16(gB + (rs + 32 * p) * 1024 + kb + cs, sB + p * 2048 + w * 512);
        __syncthreads();

#pragma unroll
        for (int kk = 0; kk < 2; ++kk) {
            const int cpos = ((kk * 4 + q4) ^ (c15 & 7)) * 8;
            bf16x8 af[4], bf[4];
#pragma unroll
            for (int mt = 0; mt < 4; ++mt)
                af[mt] = *(const bf16x8*)(sA + (wr * 64 + mt * 16 + c15) * 64 + cpos);
#pragma unroll
            for (int nt = 0; nt < 4; ++nt)
                bf[nt] = *(const bf16x8*)(sB + (wc * 64 + nt * 16 + c15) * 64 + cpos);
#pragma unroll
            for (int mt = 0; mt < 4; ++mt)
#pragma unroll
                for (int nt = 0; nt < 4; ++nt)
                    acc[mt][nt] = __builtin_amdgcn_mfma_f32_16x16x32_bf16(
                        af[mt], bf[nt], acc[mt][nt], 0, 0, 0);
        }
    }

    // ---- epilogue: bias add, per-wave LDS transpose, coalesced 16B stores ----
    // acc C-layout: out-row (A row) = wr*64 + mt*16 + q4*4 + rr,
    //               out-col (B row) = wc*64 + nt*16 + c15.
    __syncthreads();                    // sA/sB reads done; reuse smem
    const int h = cb * 2 + wc;          // head 0..15 within this mat
    float bvv[4];
#pragma unroll
    for (int nt = 0; nt < 4; ++nt)
        bvv[nt] = bias[cb * 128 + wc * 64 + nt * 16 + c15];

    u16* sc = smem + w * 4608;          // 64 rows x 72 cols per wave
    if (mat != 2) {
        u16* dst = (mat == 0) ? oq : ok;
#pragma unroll
        for (int mt = 0; mt < 4; ++mt)
#pragma unroll
            for (int nt = 0; nt < 4; ++nt)
#pragma unroll
                for (int rr = 0; rr < 4; ++rr)
                    sc[(mt * 16 + q4 * 4 + rr) * 72 + nt * 16 + c15] =
                        f2bf(acc[mt][nt][rr] + bvv[nt]);
        // 512 slots: row rl (0..63) x d-octet; 8 lanes/row -> 1KB contiguous/wave
#pragma unroll
        for (int p = 0; p < 8; ++p) {
            const int s = p * 64 + lane;
            const int rl = s >> 3, oct = (s & 7) * 8;
            bf16x8 vv = *(const bf16x8*)(sc + rl * 72 + oct);
            const int n = rb * 128 + wr * 64 + rl;
            const int bb = n >> 11, nn = n & 2047;
            *(bf16x8*)(dst + (((bb * 16 + h) * 2048) + nn) * 64 + oct) = vv;
        }
    } else {
        // V: stage transposed (d-major rows, n cols) then store along n
#pragma unroll
        for (int mt = 0; mt < 4; ++mt)
#pragma unroll
            for (int nt = 0; nt < 4; ++nt)
#pragma unroll
                for (int rr = 0; rr < 4; ++rr)
                    sc[(nt * 16 + c15) * 72 + mt * 16 + q4 * 4 + rr] =
                        f2bf(acc[mt][nt][rr] + bvv[nt]);
#pragma unroll
        for (int p = 0; p < 8; ++p) {
            const int s = p * 64 + lane;
            const int dr = s >> 3, noct = (s & 7) * 8;
            bf16x8 vv = *(const bf16x8*)(sc + dr * 72 + noct);
            const int n0 = rb * 128 + wr * 64 + noct;
            const int bb = n0 >> 11, nn = n0 & 2047;
            *(bf16x8*)(ovt + ((bb * 16 + h) * 64 + dr) * 2048 + nn) = vv;
        }
    }
}

// ---------------------------------------------------------------------------
// Kernel 2: flash attention (unchanged from R4 — verified; FETCH 12.5 MB,
// L2-resident K/V via XCD-aware grid; KVBLK=128, distance-2 prefetch with
// counted vmcnt; s_setprio around MFMA clusters).
// ---------------------------------------------------------------------------
__global__ __launch_bounds__(256, 2) void attn(
    const u16* __restrict__ qm, const u16* __restrict__ km, const u16* __restrict__ vtm,
    const float* __restrict__ mask, float* __restrict__ out)
{
    __shared__ u16 sK0[8192];          // K tile: 128 perm-key rows x 64 d
    __shared__ u16 sV0[8192];          // V^T tile: 64 d rows x 128 keys
    __shared__ u16 sK1[8192];
    __shared__ u16 sV1[8192];

    const int tid = threadIdx.x, lane = tid & 63, w = tid >> 6;
    const int c15 = lane & 15, q4 = lane >> 4;
    const int bh = blockIdx.x;         // 0..31 FASTEST -> XCD locality
    const int qt = blockIdx.y;         // q tile 0..15 (128 rows each)
    const int b = bh >> 4;

    // Q fragments (B operand of S^T = K.Q^T): rows qt*128 + w*32 + rt*16 + c15
    bf16x8 qf[2][2];
    const u16* qbase = qm + (bh * 2048 + qt * 128 + w * 32) * 64;
#pragma unroll
    for (int rt = 0; rt < 2; ++rt)
#pragma unroll
        for (int kt = 0; kt < 2; ++kt)
            qf[rt][kt] = *(const bf16x8*)(qbase + (rt * 16 + c15) * 64 + kt * 32 + q4 * 8);

    float l_acc[2] = {0.f, 0.f};
    f32x4 accO[2][4] = {};

    const u16* kbase  = km  + bh * 2048 * 64;
    const u16* vtbase = vtm + bh * 64 * 2048;   // [d][n]

    // K staging: 1024 chunks, 4/thread.  chunk c=p*256+tid -> LDS offset
    // 2048p + 8*tid = row(32p + tid>>3)*64 + (tid&7)*8; src key perm'd.
    const int rK   = tid >> 3;
    const int colK = ((tid & 7) ^ (rK & 7)) * 8;
    const int prK  = (rK & 3) | ((rK & 0x0C) << 1) | ((rK & 0x10) >> 2);
    // V staging: chunk c -> LDS offset 2048p + 8*tid = row(16p + tid>>4)*128
    // + (tid&15)*8; XOR-swizzle (tid&15) ^ (d&7).
    const int rV   = tid >> 4;
    const int colV = ((tid & 15) ^ (rV & 7)) * 8;
    const int ldsW = w * 512;                   // wave-uniform LDS dest offset

    const float* mbase = mask + b * 2048 + 8 * q4;

    auto stage = [&](u16* dK, u16* dV, int TT) {
        const u16* kg = kbase + TT * 128 * 64;
        const u16* vg = vtbase + TT * 128;
#pragma unroll
        for (int p = 0; p < 4; ++p)
            gload16(kg + (prK + 32 * p) * 64 + colK, dK + p * 2048 + ldsW);
#pragma unroll
        for (int p = 0; p < 4; ++p)
            gload16(vg + (rV + 16 * p) * 2048 + colV, dV + p * 2048 + ldsW);
    };

    // ---- compute one 64-key half from the given buffers ----
    //   sKh = K buffer + h*64 rows; pcBase = h*8 (V key-chunk offset);
    //   kb = global key base of this half.
    auto compute64 = [&](const u16* sKh, const u16* sVb, int pcBase, int kb) {
        // mask per key, pre-scaled by log2e.  (t,rr) <-> real key
        // kb + 32*(t>>1) + 8*q4 + 4*(t&1) + rr  (aligned float4 per t).
        float mkv[4][4];
#pragma unroll
        for (int t = 0; t < 4; ++t) {
            float4 m4 = *(const float4*)(mbase + kb + 32 * (t >> 1) + 4 * (t & 1));
            mkv[t][0] = m4.x * 1.4426950408889634f;
            mkv[t][1] = m4.y * 1.4426950408889634f;
            mkv[t][2] = m4.z * 1.4426950408889634f;
            mkv[t][3] = m4.w * 1.4426950408889634f;
        }

        // --- S^T = K Q^T: lane(q4,c15) reg rr = S[rho=t*16+q4*4+rr][rt*16+c15]
        f32x4 accST[4][2] = {};
        __builtin_amdgcn_s_setprio(1);
#pragma unroll
        for (int kt = 0; kt < 2; ++kt) {
            bf16x8 kf[4];
#pragma unroll
            for (int t = 0; t < 4; ++t) {
                const int cpos = (kt * 4 + q4) ^ (c15 & 7);
                kf[t] = *(const bf16x8*)(sKh + (t * 16 + c15) * 64 + cpos * 8);
            }
#pragma unroll
            for (int t = 0; t < 4; ++t)
#pragma unroll
                for (int rt = 0; rt < 2; ++rt)
                    accST[t][rt] = __builtin_amdgcn_mfma_f32_16x16x32_bf16(
                        kf[t], qf[rt][kt], accST[t][rt], 0, 0, 0);
        }
        __builtin_amdgcn_s_setprio(0);

        // --- softmax in-register: p = exp2(s*0.125*log2e + m*log2e)
        u32 pu[4][2][2];
#pragma unroll
        for (int t = 0; t < 4; ++t)
#pragma unroll
            for (int rt = 0; rt < 2; ++rt) {
                float p[4];
#pragma unroll
                for (int rr = 0; rr < 4; ++rr) {
                    p[rr] = __builtin_amdgcn_exp2f(
                        fmaf(accST[t][rt][rr], 0.18033688011112042f, mkv[t][rr]));
                    l_acc[rt] += p[rr];
                }
                pu[t][rt][0] = cvt_pk_bf16(p[0], p[1]);
                pu[t][rt][1] = cvt_pk_bf16(p[2], p[3]);
            }

        // --- PV full-K32: A-frag of lane-group q4 = real keys 32g+8q4..+7
        __builtin_amdgcn_s_setprio(1);
#pragma unroll
        for (int g = 0; g < 2; ++g) {
            // B-frags shared across rt: V[keys 32g+8q4..+7][d=nt*16+c15]
            bf16x8 vB[4];
#pragma unroll
            for (int nt = 0; nt < 4; ++nt) {
                const int d = nt * 16 + c15;
                const int pc = pcBase + ((4 * g + q4) ^ (d & 7));
                vB[nt] = *(const bf16x8*)(sVb + d * 128 + pc * 8);
            }
#pragma unroll
            for (int rt = 0; rt < 2; ++rt) {
                union { bf16x8 v; u32 u[4]; } ta;
                ta.u[0] = pu[2 * g][rt][0];
                ta.u[1] = pu[2 * g][rt][1];
                ta.u[2] = pu[2 * g + 1][rt][0];
                ta.u[3] = pu[2 * g + 1][rt][1];
#pragma unroll
                for (int nt = 0; nt < 4; ++nt)
                    accO[rt][nt] = __builtin_amdgcn_mfma_f32_16x16x32_bf16(
                        ta.v, vB[nt], accO[rt][nt], 0, 0, 0);
            }
        }
        __builtin_amdgcn_s_setprio(0);
    };

    // ---- prologue: tiles 0,1 in flight (16 loads/thread) ----
    stage(sK0, sV0, 0);
    stage(sK1, sV1, 1);

    // ---- main loop: T=0..13 (unroll 2), stage T+2 / T+3; peel 14,15 ----
#pragma unroll 1
    for (int T = 0; T < 14; T += 2) {
        VMCNT(8);                              // own tile-T loads landed
        __builtin_amdgcn_s_barrier();          // everyone's tile-T writes landed
        __builtin_amdgcn_sched_barrier(0);
        compute64(sK0, sV0, 0, T * 128);
        compute64(sK0 + 64 * 64, sV0, 8, T * 128 + 64);
        __builtin_amdgcn_s_barrier();          // all waves done reading buf0
        __builtin_amdgcn_sched_barrier(0);
        stage(sK0, sV0, T + 2);

        VMCNT(8);                              // tile T+1 landed
        __builtin_amdgcn_s_barrier();
        __builtin_amdgcn_sched_barrier(0);
        compute64(sK1, sV1, 0, (T + 1) * 128);
        compute64(sK1 + 64 * 64, sV1, 8, (T + 1) * 128 + 64);
        __builtin_amdgcn_s_barrier();          // all waves done reading buf1
        __builtin_amdgcn_sched_barrier(0);
        stage(sK1, sV1, T + 3);
    }
    // T=14 (buf0): outstanding = {S14,S15} -> wait 8
    VMCNT(8);
    __builtin_amdgcn_s_barrier();
    __builtin_amdgcn_sched_barrier(0);
    compute64(sK0, sV0, 0, 14 * 128);
    compute64(sK0 + 64 * 64, sV0, 8, 14 * 128 + 64);
    // T=15 (buf1): outstanding = {S15} -> wait 0
    VMCNT(0);
    __builtin_amdgcn_s_barrier();
    __builtin_amdgcn_sched_barrier(0);
    compute64(sK1, sV1, 0, 15 * 128);
    compute64(sK1 + 64 * 64, sV1, 8, 15 * 128 + 64);

    // --- l reduction across q4 groups -> total per qrow=c15
#pragma unroll
    for (int rt = 0; rt < 2; ++rt) {
        l_acc[rt] += __shfl_xor(l_acc[rt], 16);
        l_acc[rt] += __shfl_xor(l_acc[rt], 32);
    }

    // --- epilogue: accO C-layout row=q4*4+rr, col=c15=d
    const int h = bh & 15;
#pragma unroll
    for (int rt = 0; rt < 2; ++rt) {
        float inv[4];
#pragma unroll
        for (int rr = 0; rr < 4; ++rr)
            inv[rr] = 1.0f / __shfl(l_acc[rt], q4 * 4 + rr);
#pragma unroll
        for (int nt = 0; nt < 4; ++nt)
#pragma unroll
            for (int rr = 0; rr < 4; ++rr) {
                const int qrow = qt * 128 + w * 32 + rt * 16 + q4 * 4 + rr;
                const int d = nt * 16 + c15;
                out[(b * 2048 + qrow) * 1024 + h * 64 + d] = accO[rt][nt][rr] * inv[rr];
            }
    }
}

// ---------------------------------------------------------------------------
extern "C" void kernel_launch(void* const* d_in, const int* in_sizes, int n_in,
                              void* d_out, int out_size, void* d_ws, size_t ws_size,
                              hipStream_t stream)
{
    const float* hs   = (const float*)d_in[0];
    const float* mask = (const float*)d_in[1];
    const float* Wq   = (const float*)d_in[2];
    const float* bq   = (const float*)d_in[3];
    const float* Wk   = (const float*)d_in[4];
    const float* bk   = (const float*)d_in[5];
    const float* Wv   = (const float*)d_in[6];
    const float* bv   = (const float*)d_in[7];

    // workspace layout (u16 units)
    u16* ws   = (u16*)d_ws;
    u16* qw   = ws;                     // Q  [b,h,n,d] bf16
    u16* kw   = ws + 4194304;           // K  [b,h,n,d]
    u16* vtw  = ws + 8388608;           // V^T [b,h,d,n]
    u16* hsb  = ws + 12582912;          // hidden_states bf16 (cvt_all dst start)
    u16* wqb  = ws + 16777216;
    u16* wkb  = ws + 17825792;
    u16* wvb  = ws + 18874368;

    cvt_all<<<1024, 256, 0, stream>>>(hs, Wq, Wk, Wv, hsb);

    qkv_gemm<<<dim3(24, 32), 256, 0, stream>>>(hsb, wqb, wkb, wvb, bq, bk, bv, qw, kw, vtw);
    attn<<<dim3(32, 16), 256, 0, stream>>>(qw, kw, vtw, mask, (float*)d_out);
}

// Round 7
// 162.308 us; speedup vs baseline: 1.0991x; 1.0991x over previous
//
#include <hip/hip_runtime.h>

typedef unsigned short u16;
typedef unsigned int   u32;
typedef __attribute__((ext_vector_type(8))) short bf16x8;
typedef __attribute__((ext_vector_type(4))) float f32x4;
typedef __attribute__((ext_vector_type(2))) unsigned int u32x2;

__device__ __forceinline__ float bf2f(u16 u) { return __uint_as_float(((u32)u) << 16); }
// round-half-up (ties away): identical to RNE except exact ties; 2 VALU ops.
__device__ __forceinline__ u16 f2bf(float f) {
    return (u16)((__float_as_uint(f) + 0x8000u) >> 16);
}
// packed RNE f32->bf16 pair: one VALU op for two conversions
__device__ __forceinline__ u32 cvt_pk_bf16(float lo, float hi) {
    u32 r;
    asm("v_cvt_pk_bf16_f32 %0, %1, %2" : "=v"(r) : "v"(lo), "v"(hi));
    return r;
}
__device__ __forceinline__ void gload16(const void* g, void* l) {
    __builtin_amdgcn_global_load_lds((const __attribute__((address_space(1))) void*)g,
                                     (__attribute__((address_space(3))) void*)l, 16, 0, 0);
}
#define VMCNT(n) asm volatile("s_waitcnt vmcnt(" #n ")" ::: "memory")

// ---------------------------------------------------------------------------
// Fused fp32->bf16 conversion for hs + Wq + Wk + Wv (contiguous dsts in ws).
// ---------------------------------------------------------------------------
struct us4 { u16 x, y, z, w; };
__global__ void cvt_all(const float* __restrict__ hs, const float* __restrict__ wq,
                        const float* __restrict__ wk, const float* __restrict__ wv,
                        u16* __restrict__ dst)
{
    int i = blockIdx.x * blockDim.x + threadIdx.x;
    const int stride = gridDim.x * blockDim.x;
    us4* d4 = (us4*)dst;
    for (; i < 1835008; i += stride) {
        const float4* s4;
        int j = i;
        if (j < 1048576)      { s4 = (const float4*)hs; }
        else if (j < 1310720) { s4 = (const float4*)wq; j -= 1048576; }
        else if (j < 1572864) { s4 = (const float4*)wk; j -= 1310720; }
        else                  { s4 = (const float4*)wv; j -= 1572864; }
        float4 v = s4[j];
        us4 o;
        o.x = f2bf(v.x); o.y = f2bf(v.y); o.z = f2bf(v.z); o.w = f2bf(v.w);
        d4[i] = o;
    }
}

// ---------------------------------------------------------------------------
// Kernel 1: fused QKV projection — R7: 128x128 tile (R6 structure, compute
// and epilogue byte-identical) + the attn-proven DOUBLE-BUFFERED counted-
// vmcnt pipeline.  R6 evidence: 128^2 single-buffered regressed ~13 us vs
// the 64x128 6-block/CU version — 3 blocks/CU couldn't hide the per-step
// vmcnt(0)+barrier drain (16 steps x ~300-900 cyc L2 latency).  Fix = never
// drain: 2 LDS buffer pairs (64 KB, 2 blocks/CU), distance-2 prefetch,
// VMCNT(8)+s_barrier per step, peel last 2 steps, setprio around MFMA.
//   Grid (24, 32): blockIdx.x = mat*8+cb fastest; 24%8==0 so XCD r owns
//   cb==r for all 3 mats -> W slice 0.75 MB L2-resident.
//   Epilogue: per-wave 64x72 LDS transpose strip (smem reused after barrier),
//   16B coalesced stores.  Q,K out [b,h,n,d]; V out [b,h,d,n].
// ---------------------------------------------------------------------------
__global__ __launch_bounds__(256) void qkv_gemm(
    const u16* __restrict__ hs,
    const u16* __restrict__ Wq, const u16* __restrict__ Wk, const u16* __restrict__ Wv,
    const float* __restrict__ bq, const float* __restrict__ bk, const float* __restrict__ bv,
    u16* __restrict__ oq, u16* __restrict__ ok, u16* __restrict__ ovt)
{
    __shared__ u16 smem[32768];        // sA0 sB0 sA1 sB1, 8192 u16 each
    u16* sA0 = smem;                   // epilogue: 4 waves x 64x72 strips [0,18432)
    u16* sB0 = smem + 8192;
    u16* sA1 = smem + 16384;
    u16* sB1 = smem + 24576;

    const int tid  = threadIdx.x;
    const int lane = tid & 63;
    const int w    = tid >> 6;
    const int c15  = lane & 15;
    const int q4   = lane >> 4;
    const int mat  = blockIdx.x >> 3;   // 0=q 1=k 2=v
    const int cb   = blockIdx.x & 7;    // col block (128 cols = 2 heads)
    const int rb   = blockIdx.y;        // row block (128 rows)
    const int wr   = w >> 1, wc = w & 1;

    const u16*   W    = (mat == 0) ? Wq : (mat == 1 ? Wk : Wv);
    const float* bias = (mat == 0) ? bq : (mat == 1 ? bk : bv);

    f32x4 acc[4][4] = {};

    // staging: each 128x64 tile = 1024 16B chunks, 4/thread (chunk c=p*256+tid)
    //   row = 32p + (tid>>3), src col XOR-swizzled by row&7; LDS dest linear.
    const int rs = tid >> 3;
    const int cs = ((tid & 7) ^ (rs & 7)) * 8;
    const u16* gA = hs + (rb * 128) * 1024;
    const u16* gB = W + (cb * 128) * 1024;

    auto stageQ = [&](u16* dA, u16* dB, int kb) {
#pragma unroll
        for (int p = 0; p < 4; ++p)
            gload16(gA + (rs + 32 * p) * 1024 + kb + cs, dA + p * 2048 + w * 512);
#pragma unroll
        for (int p = 0; p < 4; ++p)
            gload16(gB + (rs + 32 * p) * 1024 + kb + cs, dB + p * 2048 + w * 512);
    };

    auto computeQ = [&](const u16* sA, const u16* sB) {
        __builtin_amdgcn_s_setprio(1);
#pragma unroll
        for (int kk = 0; kk < 2; ++kk) {
            const int cpos = ((kk * 4 + q4) ^ (c15 & 7)) * 8;
            bf16x8 af[4], bf[4];
#pragma unroll
            for (int mt = 0; mt < 4; ++mt)
                af[mt] = *(const bf16x8*)(sA + (wr * 64 + mt * 16 + c15) * 64 + cpos);
#pragma unroll
            for (int nt = 0; nt < 4; ++nt)
                bf[nt] = *(const bf16x8*)(sB + (wc * 64 + nt * 16 + c15) * 64 + cpos);
#pragma unroll
            for (int mt = 0; mt < 4; ++mt)
#pragma unroll
                for (int nt = 0; nt < 4; ++nt)
                    acc[mt][nt] = __builtin_amdgcn_mfma_f32_16x16x32_bf16(
                        af[mt], bf[nt], acc[mt][nt], 0, 0, 0);
        }
        __builtin_amdgcn_s_setprio(0);
    };

    // ---- prologue: K-steps 0,1 in flight (16 loads/thread) ----
    stageQ(sA0, sB0, 0);
    stageQ(sA1, sB1, 64);

    // ---- main loop: T=0..13 (unroll 2), stage T+2 / T+3; peel 14,15 ----
    // vmcnt: 16 outstanding in steady state; VMCNT(8) -> tile T landed.
#pragma unroll 1
    for (int T = 0; T < 14; T += 2) {
        VMCNT(8);                              // step-T loads landed
        __builtin_amdgcn_s_barrier();          // everyone's step-T writes landed
        __builtin_amdgcn_sched_barrier(0);
        computeQ(sA0, sB0);
        __builtin_amdgcn_s_barrier();          // all waves done reading buf0
        __builtin_amdgcn_sched_barrier(0);
        stageQ(sA0, sB0, (T + 2) * 64);

        VMCNT(8);                              // step T+1 landed
        __builtin_amdgcn_s_barrier();
        __builtin_amdgcn_sched_barrier(0);
        computeQ(sA1, sB1);
        __builtin_amdgcn_s_barrier();          // all waves done reading buf1
        __builtin_amdgcn_sched_barrier(0);
        stageQ(sA1, sB1, (T + 3) * 64);
    }
    // T=14 (buf0): outstanding = {S14,S15} -> wait 8
    VMCNT(8);
    __builtin_amdgcn_s_barrier();
    __builtin_amdgcn_sched_barrier(0);
    computeQ(sA0, sB0);
    // T=15 (buf1): outstanding = {S15} -> wait 0
    VMCNT(0);
    __builtin_amdgcn_s_barrier();
    __builtin_amdgcn_sched_barrier(0);
    computeQ(sA1, sB1);

    // ---- epilogue: bias add, per-wave LDS transpose, coalesced 16B stores ----
    // acc C-layout: out-row (A row) = wr*64 + mt*16 + q4*4 + rr,
    //               out-col (B row) = wc*64 + nt*16 + c15.
    __syncthreads();                    // LDS reads done; reuse smem
    const int h = cb * 2 + wc;          // head 0..15 within this mat
    float bvv[4];
#pragma unroll
    for (int nt = 0; nt < 4; ++nt)
        bvv[nt] = bias[cb * 128 + wc * 64 + nt * 16 + c15];

    u16* sc = smem + w * 4608;          // 64 rows x 72 cols per wave
    if (mat != 2) {
        u16* dst = (mat == 0) ? oq : ok;
#pragma unroll
        for (int mt = 0; mt < 4; ++mt)
#pragma unroll
            for (int nt = 0; nt < 4; ++nt)
#pragma unroll
                for (int rr = 0; rr < 4; ++rr)
                    sc[(mt * 16 + q4 * 4 + rr) * 72 + nt * 16 + c15] =
                        f2bf(acc[mt][nt][rr] + bvv[nt]);
        // 512 slots: row rl (0..63) x d-octet; 8 lanes/row -> 1KB contiguous/wave
#pragma unroll
        for (int p = 0; p < 8; ++p) {
            const int s = p * 64 + lane;
            const int rl = s >> 3, oct = (s & 7) * 8;
            bf16x8 vv = *(const bf16x8*)(sc + rl * 72 + oct);
            const int n = rb * 128 + wr * 64 + rl;
            const int bb = n >> 11, nn = n & 2047;
            *(bf16x8*)(dst + (((bb * 16 + h) * 2048) + nn) * 64 + oct) = vv;
        }
    } else {
        // V: stage transposed (d-major rows, n cols) then store along n
#pragma unroll
        for (int mt = 0; mt < 4; ++mt)
#pragma unroll
            for (int nt = 0; nt < 4; ++nt)
#pragma unroll
                for (int rr = 0; rr < 4; ++rr)
                    sc[(nt * 16 + c15) * 72 + mt * 16 + q4 * 4 + rr] =
                        f2bf(acc[mt][nt][rr] + bvv[nt]);
#pragma unroll
        for (int p = 0; p < 8; ++p) {
            const int s = p * 64 + lane;
            const int dr = s >> 3, noct = (s & 7) * 8;
            bf16x8 vv = *(const bf16x8*)(sc + dr * 72 + noct);
            const int n0 = rb * 128 + wr * 64 + noct;
            const int bb = n0 >> 11, nn = n0 & 2047;
            *(bf16x8*)(ovt + ((bb * 16 + h) * 64 + dr) * 2048 + nn) = vv;
        }
    }
}

// ---------------------------------------------------------------------------
// Kernel 2: flash attention (unchanged from R4 — verified; FETCH 12.5 MB,
// L2-resident K/V via XCD-aware grid; KVBLK=128, distance-2 prefetch with
// counted vmcnt; s_setprio around MFMA clusters).
// ---------------------------------------------------------------------------
__global__ __launch_bounds__(256, 2) void attn(
    const u16* __restrict__ qm, const u16* __restrict__ km, const u16* __restrict__ vtm,
    const float* __restrict__ mask, float* __restrict__ out)
{
    __shared__ u16 sK0[8192];          // K tile: 128 perm-key rows x 64 d
    __shared__ u16 sV0[8192];          // V^T tile: 64 d rows x 128 keys
    __shared__ u16 sK1[8192];
    __shared__ u16 sV1[8192];

    const int tid = threadIdx.x, lane = tid & 63, w = tid >> 6;
    const int c15 = lane & 15, q4 = lane >> 4;
    const int bh = blockIdx.x;         // 0..31 FASTEST -> XCD locality
    const int qt = blockIdx.y;         // q tile 0..15 (128 rows each)
    const int b = bh >> 4;

    // Q fragments (B operand of S^T = K.Q^T): rows qt*128 + w*32 + rt*16 + c15
    bf16x8 qf[2][2];
    const u16* qbase = qm + (bh * 2048 + qt * 128 + w * 32) * 64;
#pragma unroll
    for (int rt = 0; rt < 2; ++rt)
#pragma unroll
        for (int kt = 0; kt < 2; ++kt)
            qf[rt][kt] = *(const bf16x8*)(qbase + (rt * 16 + c15) * 64 + kt * 32 + q4 * 8);

    float l_acc[2] = {0.f, 0.f};
    f32x4 accO[2][4] = {};

    const u16* kbase  = km  + bh * 2048 * 64;
    const u16* vtbase = vtm + bh * 64 * 2048;   // [d][n]

    // K staging: 1024 chunks, 4/thread.  chunk c=p*256+tid -> LDS offset
    // 2048p + 8*tid = row(32p + tid>>3)*64 + (tid&7)*8; src key perm'd.
    const int rK   = tid >> 3;
    const int colK = ((tid & 7) ^ (rK & 7)) * 8;
    const int prK  = (rK & 3) | ((rK & 0x0C) << 1) | ((rK & 0x10) >> 2);
    // V staging: chunk c -> LDS offset 2048p + 8*tid = row(16p + tid>>4)*128
    // + (tid&15)*8; XOR-swizzle (tid&15) ^ (d&7).
    const int rV   = tid >> 4;
    const int colV = ((tid & 15) ^ (rV & 7)) * 8;
    const int ldsW = w * 512;                   // wave-uniform LDS dest offset

    const float* mbase = mask + b * 2048 + 8 * q4;

    auto stage = [&](u16* dK, u16* dV, int TT) {
        const u16* kg = kbase + TT * 128 * 64;
        const u16* vg = vtbase + TT * 128;
#pragma unroll
        for (int p = 0; p < 4; ++p)
            gload16(kg + (prK + 32 * p) * 64 + colK, dK + p * 2048 + ldsW);
#pragma unroll
        for (int p = 0; p < 4; ++p)
            gload16(vg + (rV + 16 * p) * 2048 + colV, dV + p * 2048 + ldsW);
    };

    // ---- compute one 64-key half from the given buffers ----
    //   sKh = K buffer + h*64 rows; pcBase = h*8 (V key-chunk offset);
    //   kb = global key base of this half.
    auto compute64 = [&](const u16* sKh, const u16* sVb, int pcBase, int kb) {
        // mask per key, pre-scaled by log2e.  (t,rr) <-> real key
        // kb + 32*(t>>1) + 8*q4 + 4*(t&1) + rr  (aligned float4 per t).
        float mkv[4][4];
#pragma unroll
        for (int t = 0; t < 4; ++t) {
            float4 m4 = *(const float4*)(mbase + kb + 32 * (t >> 1) + 4 * (t & 1));
            mkv[t][0] = m4.x * 1.4426950408889634f;
            mkv[t][1] = m4.y * 1.4426950408889634f;
            mkv[t][2] = m4.z * 1.4426950408889634f;
            mkv[t][3] = m4.w * 1.4426950408889634f;
        }

        // --- S^T = K Q^T: lane(q4,c15) reg rr = S[rho=t*16+q4*4+rr][rt*16+c15]
        f32x4 accST[4][2] = {};
        __builtin_amdgcn_s_setprio(1);
#pragma unroll
        for (int kt = 0; kt < 2; ++kt) {
            bf16x8 kf[4];
#pragma unroll
            for (int t = 0; t < 4; ++t) {
                const int cpos = (kt * 4 + q4) ^ (c15 & 7);
                kf[t] = *(const bf16x8*)(sKh + (t * 16 + c15) * 64 + cpos * 8);
            }
#pragma unroll
            for (int t = 0; t < 4; ++t)
#pragma unroll
                for (int rt = 0; rt < 2; ++rt)
                    accST[t][rt] = __builtin_amdgcn_mfma_f32_16x16x32_bf16(
                        kf[t], qf[rt][kt], accST[t][rt], 0, 0, 0);
        }
        __builtin_amdgcn_s_setprio(0);

        // --- softmax in-register: p = exp2(s*0.125*log2e + m*log2e)
        u32 pu[4][2][2];
#pragma unroll
        for (int t = 0; t < 4; ++t)
#pragma unroll
            for (int rt = 0; rt < 2; ++rt) {
                float p[4];
#pragma unroll
                for (int rr = 0; rr < 4; ++rr) {
                    p[rr] = __builtin_amdgcn_exp2f(
                        fmaf(accST[t][rt][rr], 0.18033688011112042f, mkv[t][rr]));
                    l_acc[rt] += p[rr];
                }
                pu[t][rt][0] = cvt_pk_bf16(p[0], p[1]);
                pu[t][rt][1] = cvt_pk_bf16(p[2], p[3]);
            }

        // --- PV full-K32: A-frag of lane-group q4 = real keys 32g+8q4..+7
        __builtin_amdgcn_s_setprio(1);
#pragma unroll
        for (int g = 0; g < 2; ++g) {
            // B-frags shared across rt: V[keys 32g+8q4..+7][d=nt*16+c15]
            bf16x8 vB[4];
#pragma unroll
            for (int nt = 0; nt < 4; ++nt) {
                const int d = nt * 16 + c15;
                const int pc = pcBase + ((4 * g + q4) ^ (d & 7));
                vB[nt] = *(const bf16x8*)(sVb + d * 128 + pc * 8);
            }
#pragma unroll
            for (int rt = 0; rt < 2; ++rt) {
                union { bf16x8 v; u32 u[4]; } ta;
                ta.u[0] = pu[2 * g][rt][0];
                ta.u[1] = pu[2 * g][rt][1];
                ta.u[2] = pu[2 * g + 1][rt][0];
                ta.u[3] = pu[2 * g + 1][rt][1];
#pragma unroll
                for (int nt = 0; nt < 4; ++nt)
                    accO[rt][nt] = __builtin_amdgcn_mfma_f32_16x16x32_bf16(
                        ta.v, vB[nt], accO[rt][nt], 0, 0, 0);
            }
        }
        __builtin_amdgcn_s_setprio(0);
    };

    // ---- prologue: tiles 0,1 in flight (16 loads/thread) ----
    stage(sK0, sV0, 0);
    stage(sK1, sV1, 1);

    // ---- main loop: T=0..13 (unroll 2), stage T+2 / T+3; peel 14,15 ----
#pragma unroll 1
    for (int T = 0; T < 14; T += 2) {
        VMCNT(8);                              // own tile-T loads landed
        __builtin_amdgcn_s_barrier();          // everyone's tile-T writes landed
        __builtin_amdgcn_sched_barrier(0);
        compute64(sK0, sV0, 0, T * 128);
        compute64(sK0 + 64 * 64, sV0, 8, T * 128 + 64);
        __builtin_amdgcn_s_barrier();          // all waves done reading buf0
        __builtin_amdgcn_sched_barrier(0);
        stage(sK0, sV0, T + 2);

        VMCNT(8);                              // tile T+1 landed
        __builtin_amdgcn_s_barrier();
        __builtin_amdgcn_sched_barrier(0);
        compute64(sK1, sV1, 0, (T + 1) * 128);
        compute64(sK1 + 64 * 64, sV1, 8, (T + 1) * 128 + 64);
        __builtin_amdgcn_s_barrier();          // all waves done reading buf1
        __builtin_amdgcn_sched_barrier(0);
        stage(sK1, sV1, T + 3);
    }
    // T=14 (buf0): outstanding = {S14,S15} -> wait 8
    VMCNT(8);
    __builtin_amdgcn_s_barrier();
    __builtin_amdgcn_sched_barrier(0);
    compute64(sK0, sV0, 0, 14 * 128);
    compute64(sK0 + 64 * 64, sV0, 8, 14 * 128 + 64);
    // T=15 (buf1): outstanding = {S15} -> wait 0
    VMCNT(0);
    __builtin_amdgcn_s_barrier();
    __builtin_amdgcn_sched_barrier(0);
    compute64(sK1, sV1, 0, 15 * 128);
    compute64(sK1 + 64 * 64, sV1, 8, 15 * 128 + 64);

    // --- l reduction across q4 groups -> total per qrow=c15
#pragma unroll
    for (int rt = 0; rt < 2; ++rt) {
        l_acc[rt] += __shfl_xor(l_acc[rt], 16);
        l_acc[rt] += __shfl_xor(l_acc[rt], 32);
    }

    // --- epilogue: accO C-layout row=q4*4+rr, col=c15=d
    const int h = bh & 15;
#pragma unroll
    for (int rt = 0; rt < 2; ++rt) {
        float inv[4];
#pragma unroll
        for (int rr = 0; rr < 4; ++rr)
            inv[rr] = 1.0f / __shfl(l_acc[rt], q4 * 4 + rr);
#pragma unroll
        for (int nt = 0; nt < 4; ++nt)
#pragma unroll
            for (int rr = 0; rr < 4; ++rr) {
                const int qrow = qt * 128 + w * 32 + rt * 16 + q4 * 4 + rr;
                const int d = nt * 16 + c15;
                out[(b * 2048 + qrow) * 1024 + h * 64 + d] = accO[rt][nt][rr] * inv[rr];
            }
    }
}

// ---------------------------------------------------------------------------
extern "C" void kernel_launch(void* const* d_in, const int* in_sizes, int n_in,
                              void* d_out, int out_size, void* d_ws, size_t ws_size,
                              hipStream_t stream)
{
    const float* hs   = (const float*)d_in[0];
    const float* mask = (const float*)d_in[1];
    const float* Wq   = (const float*)d_in[2];
    const float* bq   = (const float*)d_in[3];
    const float* Wk   = (const float*)d_in[4];
    const float* bk   = (const float*)d_in[5];
    const float* Wv   = (const float*)d_in[6];
    const float* bv   = (const float*)d_in[7];

    // workspace layout (u16 units)
    u16* ws   = (u16*)d_ws;
    u16* qw   = ws;                     // Q  [b,h,n,d] bf16
    u16* kw   = ws + 4194304;           // K  [b,h,n,d]
    u16* vtw  = ws + 8388608;           // V^T [b,h,d,n]
    u16* hsb  = ws + 12582912;          // hidden_states bf16 (cvt_all dst start)
    u16* wqb  = ws + 16777216;
    u16* wkb  = ws + 17825792;
    u16* wvb  = ws + 18874368;

    cvt_all<<<1024, 256, 0, stream>>>(hs, Wq, Wk, Wv, hsb);

    qkv_gemm<<<dim3(24, 32), 256, 0, stream>>>(hsb, wqb, wkb, wvb, bq, bk, bv, qw, kw, vtw);
    attn<<<dim3(32, 16), 256, 0, stream>>>(qw, kw, vtw, mask, (float*)d_out);
}